// Round 4
// baseline (2492.783 us; speedup 1.0000x reference)
//
#include <hip/hip_runtime.h>

// RecurrentActorCritic B=512,T=512,S=64,H=128,A=8 (fp32 I/O).
// Grid 256 x 768 threads: one block per CU, TWO batch chains per block.
// Each thread owns ONE weight row in regs (64 h2t): tid<384 -> W_ih row tid;
// tid>=384 -> W_hh row tid-384. Threads 256-511 also own one W_feat row (32 h2t).
// R3 post-mortem: union{h8t;h2t[4]} temporaries defeated SROA -> 110 GB scratch
// traffic (FETCH 54 GB + WRITE 59 GB matches 512 B/thread/step exactly).
// R4: no unions, no h8t — direct h2t LDS loads (wave-uniform address =>
// broadcast, free) and plain float2->h2t weight conversion loops.

typedef _Float16 h2t __attribute__((ext_vector_type(2)));

__device__ __forceinline__ float dot2a(h2t a, h2t b, float c) {
    return __builtin_amdgcn_fdot2(a, b, c, false);
}

#define BB 512
#define TT 512
#define SS 64
#define HH 128
#define AA 8
#define NT 768

__global__ __launch_bounds__(NT, 3) void rac_kernel(
    const float* __restrict__ x,    // (B,T,S)
    const float* __restrict__ hx,   // (1,B,H)
    const int*   __restrict__ done, // (B,T)
    const float* __restrict__ Wf,   // (H,S)
    const float* __restrict__ bfe,  // (H)
    const float* __restrict__ gf,   // (H)
    const float* __restrict__ btf,  // (H)
    const float* __restrict__ Wih,  // (3H,H)
    const float* __restrict__ Whh,  // (3H,H)
    const float* __restrict__ bih,  // (3H)
    const float* __restrict__ bhh,  // (3H)
    const float* __restrict__ gr,   // (H)
    const float* __restrict__ btr,  // (H)
    const float* __restrict__ Wp,   // (A,H)
    const float* __restrict__ bp,   // (A)
    const float* __restrict__ Wv,   // (1,H)
    const float* __restrict__ bv,   // (1)
    float* __restrict__ out)
{
    const int tid = threadIdx.x;
    const int b0  = blockIdx.x * 2;

    __shared__ __align__(16) _Float16 zh[2][HH];   // z_{t+1} (fp16)
    __shared__ __align__(16) _Float16 hsh[2][HH];  // h_{t-1} masked (fp16)
    __shared__ __align__(16) _Float16 xh[2][SS];   // x_{t+1} (fp16)
    __shared__ __align__(16) float gxl[2][3*HH];
    __shared__ __align__(16) float ghl[2][3*HH];
    __shared__ __align__(16) float yl[2][HH];      // y_{t-1}
    __shared__ __align__(16) float fraw[2][HH];    // raw feature pre-LN
    __shared__ float fred[4][2];                   // feature LN partials (waves 4-7)
    __shared__ float hred[4][2];                   // h LN partials (waves 0-3)

    const bool isGate = tid < 256;
    const bool isProd = tid < 384;
    const bool isFeat = (tid >= 256) && (tid < 512);
    const bool isXld  = (tid >= 512) && (tid < 640);
    const bool isHead = tid >= 512;

    // ---- one main matvec row per thread (64 h2t = 64 VGPR) ----
    h2t wmat[64];
    {
        const float* wsrc = isProd ? (Wih + tid * HH) : (Whh + (tid - 384) * HH);
        const float2* p2 = (const float2*)wsrc;
        #pragma unroll
        for (int q = 0; q < 64; ++q) {
            float2 v = p2[q];
            h2t a; a.x = (_Float16)v.x; a.y = (_Float16)v.y;
            wmat[q] = a;
        }
    }
    const float bias_mv = isProd ? bih[tid] : bhh[tid - 384];

    // ---- feature row (threads 256-511): 32 h2t ----
    h2t wfr[32];
    float bfr = 0.f;
    int fc = 0, fj = 0;
    if (isFeat) {
        fc = (tid - 256) >> 7; fj = (tid - 256) & 127;
        const float2* p2 = (const float2*)(Wf + fj * SS);
        #pragma unroll
        for (int q = 0; q < 32; ++q) {
            float2 v = p2[q];
            h2t a; a.x = (_Float16)v.x; a.y = (_Float16)v.y;
            wfr[q] = a;
        }
        bfr = bfe[fj];
    }

    // ---- gate-owner regs (threads 0-255: (chain gc, dim gj)) ----
    int gc = 0, gj = 0;
    float gfr = 0.f, btfr = 0.f, grr = 0.f, btrr = 0.f, hprev = 0.f;
    if (isGate) {
        gc = tid >> 7; gj = tid & 127;
        gfr = gf[gj]; btfr = btf[gj]; grr = gr[gj]; btrr = btr[gj];
        hprev = hx[(b0 + gc) * HH + gj];
        hsh[gc][gj] = (_Float16)hprev;
    }

    // ---- head regs (threads 512-767: 16 groups of 16; groups 0,1 take 2nd task) ----
    float wh0[8], wh1[8];
    float bp0 = 0.f, bp1 = 0.f;
    int hi16 = 0, tk0 = 0, tk1 = -1;
    if (isHead) {
        int hid = tid - 512; int hg = hid >> 4; hi16 = hid & 15;
        tk0 = hg;                         // tasks 0..15
        tk1 = (hg < 2) ? (16 + hg) : -1;  // tasks 16,17
        {
            int k = tk0 % 9;
            const float* wr = (k < 8) ? (Wp + k * HH) : Wv;
            #pragma unroll
            for (int e = 0; e < 8; ++e) wh0[e] = wr[hi16 * 8 + e];
            bp0 = (k < 8) ? bp[k] : bv[0];
        }
        if (tk1 >= 0) {
            int k = tk1 % 9;
            const float* wr = (k < 8) ? (Wp + k * HH) : Wv;
            #pragma unroll
            for (int e = 0; e < 8; ++e) wh1[e] = wr[hi16 * 8 + e];
            bp1 = (k < 8) ? bp[k] : bv[0];
        } else {
            #pragma unroll
            for (int e = 0; e < 8; ++e) wh1[e] = 0.f;
        }
    }

    // ---- x prefetch regs (threads 512-639) ----
    int xc = 0, xe = 0;
    const float* xbase = nullptr;
    float xr0 = 0.f, xr1 = 0.f;
    if (isXld) {
        int xi = tid - 512; xc = xi >> 6; xe = xi & 63;
        xbase = x + (size_t)(b0 + xc) * TT * SS + xe;
        float xa = xbase[0];            // x(0)
        xr1 = xbase[SS];                // x(1) held until P2
        xr0 = xbase[2 * SS];            // x(2), slot (0+2)&1 = 0
        xh[xc][xe] = (_Float16)xa;
    }
    __syncthreads();   // P0: xh=x0, hsh=hx visible

    // ---- prologue: z_0 ----
    if (isFeat) {
        float f0 = bfr, f1 = 0.f;
        const h2t* px = (const h2t*)xh[fc];
        #pragma unroll
        for (int k = 0; k < 32; k += 2) {
            f0 = dot2a(wfr[k],     px[k],     f0);
            f1 = dot2a(wfr[k + 1], px[k + 1], f1);
        }
        float fv = f0 + f1;
        fraw[fc][fj] = fv;
        float s = fv, q = fv * fv;
        #pragma unroll
        for (int m = 1; m < 64; m <<= 1) { s += __shfl_xor(s, m); q += __shfl_xor(q, m); }
        if ((tid & 63) == 0) { int w = (tid >> 6) - 4; fred[w][0] = s; fred[w][1] = q; }
    }
    __syncthreads();   // P1
    if (isGate) {
        float s = fred[2 * gc][0] + fred[2 * gc + 1][0];
        float q = fred[2 * gc][1] + fred[2 * gc + 1][1];
        float mu = s * (1.f / 128.f);
        float rstd = rsqrtf(q * (1.f / 128.f) - mu * mu + 1e-5f);
        float z = (fraw[gc][gj] - mu) * rstd * gfr + btfr;
        zh[gc][gj] = (_Float16)fmaxf(z, 0.f);
    }
    if (isXld) xh[xc][xe] = (_Float16)xr1;   // stage x(1); xr1 now a free slot
    __syncthreads();   // P2

    float hnew_keep = 0.f;
    const int VALO = BB * TT * AA;
    const int HFIN = VALO + BB * TT;

    for (int i = 0; i <= TT; ++i) {
        const bool live = i < TT;
        // ================= Seg A =================
        int dreg = 0;
        if (isGate && live) dreg = done[(b0 + gc) * TT + i];
        if (isXld && i < TT - 3) {
            float v = xbase[(size_t)(i + 3) * SS];
            if (((i + 3) & 1) == 0) xr0 = v; else xr1 = v;
        }
        if (isGate && i >= 1) {   // finalize y_{i-1} from hred + kept h_new
            float s = hred[2 * gc][0] + hred[2 * gc + 1][0];
            float q = hred[2 * gc][1] + hred[2 * gc + 1][1];
            float mu = s * (1.f / 128.f);
            float rstd = rsqrtf(q * (1.f / 128.f) - mu * mu + 1e-5f);
            yl[gc][gj] = (hnew_keep - mu) * rstd * grr + btrr;
        }
        if (live) {   // main matvecs, both chains interleaved (ILP 2)
            const _Float16* va; const _Float16* vb; int r;
            if (isProd) { va = zh[0];  vb = zh[1];  r = tid; }
            else        { va = hsh[0]; vb = hsh[1]; r = tid - 384; }
            const h2t* pa = (const h2t*)va;
            const h2t* pb = (const h2t*)vb;
            float a0 = bias_mv, a1 = bias_mv;
            #pragma unroll
            for (int k = 0; k < 64; ++k) {
                a0 = dot2a(wmat[k], pa[k], a0);
                a1 = dot2a(wmat[k], pb[k], a1);
            }
            if (isProd) { gxl[0][r] = a0; gxl[1][r] = a1; }
            else        { ghl[0][r] = a0; ghl[1][r] = a1; }
        }
        if (isFeat && i < TT - 1) {   // feature dots for z_{i+1} from xh=x_{i+1}
            float f0 = bfr, f1 = 0.f;
            const h2t* px = (const h2t*)xh[fc];
            #pragma unroll
            for (int k = 0; k < 32; k += 2) {
                f0 = dot2a(wfr[k],     px[k],     f0);
                f1 = dot2a(wfr[k + 1], px[k + 1], f1);
            }
            float fv = f0 + f1;
            fraw[fc][fj] = fv;
            float s = fv, q = fv * fv;
            #pragma unroll
            for (int m = 1; m < 64; m <<= 1) { s += __shfl_xor(s, m); q += __shfl_xor(q, m); }
            if ((tid & 63) == 0) { int w = (tid >> 6) - 4; fred[w][0] = s; fred[w][1] = q; }
        }
        __syncthreads();
        // ================= Seg B =================
        if (isGate) {
            if (i < TT - 1) {   // LN+relu -> z_{i+1}
                float s = fred[2 * gc][0] + fred[2 * gc + 1][0];
                float q = fred[2 * gc][1] + fred[2 * gc + 1][1];
                float mu = s * (1.f / 128.f);
                float rstd = rsqrtf(q * (1.f / 128.f) - mu * mu + 1e-5f);
                float z = (fraw[gc][gj] - mu) * rstd * gfr + btfr;
                zh[gc][gj] = (_Float16)fmaxf(z, 0.f);
            }
            if (live) {         // GRU gates for step i
                float xr_ = gxl[gc][gj],          hr_ = ghl[gc][gj];
                float xz_ = gxl[gc][HH + gj],     hz_ = ghl[gc][HH + gj];
                float xn_ = gxl[gc][2 * HH + gj], hn_ = ghl[gc][2 * HH + gj];
                float r_ = 1.f / (1.f + __expf(-(xr_ + hr_)));
                float u_ = 1.f / (1.f + __expf(-(xz_ + hz_)));
                float a_ = xn_ + r_ * hn_;
                a_ = fminf(fmaxf(a_, -20.f), 20.f);
                float e2 = __expf(2.f * a_);
                float n_ = (e2 - 1.f) / (e2 + 1.f);
                float hn2 = (1.f - u_) * n_ + u_ * hprev;
                hnew_keep = hn2;
                float s = hn2, q = hn2 * hn2;
                #pragma unroll
                for (int m = 1; m < 64; m <<= 1) { s += __shfl_xor(s, m); q += __shfl_xor(q, m); }
                if ((tid & 63) == 0) { int w = tid >> 6; hred[w][0] = s; hred[w][1] = q; }
                float hm = hn2 * (dreg ? 0.f : 1.f);
                hprev = hm;
                hsh[gc][gj] = (_Float16)hm;
                if (i == TT - 1) out[HFIN + (b0 + gc) * HH + gj] = hm;
            }
        }
        if (isHead && i >= 1) {   // heads for t = i-1 from yl
            int t = i - 1;
            {
                int c = tk0 / 9, k = tk0 % 9;
                const float4* py = (const float4*)yl[c];
                float4 y0 = py[hi16 * 2], y1 = py[hi16 * 2 + 1];
                float p = y0.x * wh0[0] + y0.y * wh0[1] + y0.z * wh0[2] + y0.w * wh0[3]
                        + y1.x * wh0[4] + y1.y * wh0[5] + y1.z * wh0[6] + y1.w * wh0[7];
                #pragma unroll
                for (int m = 8; m >= 1; m >>= 1) p += __shfl_xor(p, m);
                if (hi16 == 0) {
                    int bc = b0 + c;
                    if (k < 8) out[((size_t)bc * TT + t) * AA + k] = p + bp0;
                    else       out[VALO + bc * TT + t] = p + bp0;
                }
            }
            if (tk1 >= 0) {
                int c = tk1 / 9, k = tk1 % 9;
                const float4* py = (const float4*)yl[c];
                float4 y0 = py[hi16 * 2], y1 = py[hi16 * 2 + 1];
                float p = y0.x * wh1[0] + y0.y * wh1[1] + y0.z * wh1[2] + y0.w * wh1[3]
                        + y1.x * wh1[4] + y1.y * wh1[5] + y1.z * wh1[6] + y1.w * wh1[7];
                #pragma unroll
                for (int m = 8; m >= 1; m >>= 1) p += __shfl_xor(p, m);
                if (hi16 == 0) {
                    int bc = b0 + c;
                    if (k < 8) out[((size_t)bc * TT + t) * AA + k] = p + bp1;
                    else       out[VALO + bc * TT + t] = p + bp1;
                }
            }
        }
        if (isXld && i < TT - 2) {   // stage x(i+2) reg -> LDS
            float v = (((i + 2) & 1) == 0) ? xr0 : xr1;
            xh[xc][xe] = (_Float16)v;
        }
        __syncthreads();
    }
}

extern "C" void kernel_launch(void* const* d_in, const int* in_sizes, int n_in,
                              void* d_out, int out_size, void* d_ws, size_t ws_size,
                              hipStream_t stream) {
    const float* x   = (const float*)d_in[0];
    const float* hx  = (const float*)d_in[1];
    const int*   dn  = (const int*)d_in[2];
    const float* Wf  = (const float*)d_in[3];
    const float* bfe = (const float*)d_in[4];
    const float* gf  = (const float*)d_in[5];
    const float* btf = (const float*)d_in[6];
    const float* Wih = (const float*)d_in[7];
    const float* Whh = (const float*)d_in[8];
    const float* bih = (const float*)d_in[9];
    const float* bhh = (const float*)d_in[10];
    const float* gr  = (const float*)d_in[11];
    const float* btr = (const float*)d_in[12];
    const float* Wp  = (const float*)d_in[13];
    const float* bp  = (const float*)d_in[14];
    const float* Wv  = (const float*)d_in[15];
    const float* bv  = (const float*)d_in[16];
    float* out = (float*)d_out;

    hipLaunchKernelGGL(rac_kernel, dim3(BB / 2), dim3(NT), 0, stream,
                       x, hx, dn, Wf, bfe, gf, btf, Wih, Whh, bih, bhh,
                       gr, btr, Wp, bp, Wv, bv, out);
}

// Round 5
// 1936.307 us; speedup vs baseline: 1.2874x; 1.2874x over previous
//
#include <hip/hip_runtime.h>

// RecurrentActorCritic B=512,T=512,S=64,H=128,A=8 (fp32 I/O).
// Grid 256 x 768 threads, one block/CU, two batch chains per block.
// R2-R4 post-mortem: per-thread weight ARRAYS (wmat[64]/wfr[32]) were never
// promoted out of scratch (VGPR_Count pinned at 84, ~115 GB scratch traffic
// per dispatch). R5: weights are ext_vector SSA values (f16v = 16 floats,
// each float = packed fp16 pair), accessed only with literal-constant lane
// indices via macros -> nothing alloca-shaped remains. LDS operands read as
// float4 (b128 broadcast), bitcast per-lane to h2t for v_dot2_f32_f16.
// Roles: tid 0-255 gate/LN (owns W_ih rows too), 256-383 W_ih rows,
// 384-767 W_hh rows, 512-767 feature rows + heads, 512-639 x prefetch.

typedef _Float16 h2t __attribute__((ext_vector_type(2)));
typedef float f16v __attribute__((ext_vector_type(16)));
typedef float f8v  __attribute__((ext_vector_type(8)));

__device__ __forceinline__ float dot2a(h2t a, h2t b, float c) {
    return __builtin_amdgcn_fdot2(a, b, c, false);
}
__device__ __forceinline__ h2t f2h(float f) { return __builtin_bit_cast(h2t, f); }
__device__ __forceinline__ float pk2(float lo, float hi) {
    h2t a; a.x = (_Float16)lo; a.y = (_Float16)hi;
    return __builtin_bit_cast(float, a);
}

#define BB 512
#define TT 512
#define SS 64
#define HH 128
#define AA 8
#define NT 768

// load 16 packed pairs (32 floats) from float2* P2 at pair-offset OFS into f16v WV
#define LDW16(WV, P2, OFS) { float2 v_; \
    v_=(P2)[(OFS)+0];  WV[0] =pk2(v_.x,v_.y); v_=(P2)[(OFS)+1];  WV[1] =pk2(v_.x,v_.y); \
    v_=(P2)[(OFS)+2];  WV[2] =pk2(v_.x,v_.y); v_=(P2)[(OFS)+3];  WV[3] =pk2(v_.x,v_.y); \
    v_=(P2)[(OFS)+4];  WV[4] =pk2(v_.x,v_.y); v_=(P2)[(OFS)+5];  WV[5] =pk2(v_.x,v_.y); \
    v_=(P2)[(OFS)+6];  WV[6] =pk2(v_.x,v_.y); v_=(P2)[(OFS)+7];  WV[7] =pk2(v_.x,v_.y); \
    v_=(P2)[(OFS)+8];  WV[8] =pk2(v_.x,v_.y); v_=(P2)[(OFS)+9];  WV[9] =pk2(v_.x,v_.y); \
    v_=(P2)[(OFS)+10]; WV[10]=pk2(v_.x,v_.y); v_=(P2)[(OFS)+11]; WV[11]=pk2(v_.x,v_.y); \
    v_=(P2)[(OFS)+12]; WV[12]=pk2(v_.x,v_.y); v_=(P2)[(OFS)+13]; WV[13]=pk2(v_.x,v_.y); \
    v_=(P2)[(OFS)+14]; WV[14]=pk2(v_.x,v_.y); v_=(P2)[(OFS)+15]; WV[15]=pk2(v_.x,v_.y); }

#define DOT4(WV, J, UA, UB) \
    a0=dot2a(f2h(WV[(J)+0]),f2h(UA.x),a0); a1=dot2a(f2h(WV[(J)+0]),f2h(UB.x),a1); \
    a0=dot2a(f2h(WV[(J)+1]),f2h(UA.y),a0); a1=dot2a(f2h(WV[(J)+1]),f2h(UB.y),a1); \
    a0=dot2a(f2h(WV[(J)+2]),f2h(UA.z),a0); a1=dot2a(f2h(WV[(J)+2]),f2h(UB.z),a1); \
    a0=dot2a(f2h(WV[(J)+3]),f2h(UA.w),a0); a1=dot2a(f2h(WV[(J)+3]),f2h(UB.w),a1);

#define MVC(WV, OFS) { float4 ua_, ub_; \
    ua_=pa4[(OFS)+0]; ub_=pb4[(OFS)+0]; DOT4(WV,0, ua_,ub_) \
    ua_=pa4[(OFS)+1]; ub_=pb4[(OFS)+1]; DOT4(WV,4, ua_,ub_) \
    ua_=pa4[(OFS)+2]; ub_=pb4[(OFS)+2]; DOT4(WV,8, ua_,ub_) \
    ua_=pa4[(OFS)+3]; ub_=pb4[(OFS)+3]; DOT4(WV,12,ua_,ub_) }

#define FDOT4(WV, J, UX) \
    f0=dot2a(f2h(WV[(J)+0]),f2h(UX.x),f0); f1=dot2a(f2h(WV[(J)+1]),f2h(UX.y),f1); \
    f0=dot2a(f2h(WV[(J)+2]),f2h(UX.z),f0); f1=dot2a(f2h(WV[(J)+3]),f2h(UX.w),f1);

#define FEATMV { float4 ux_; \
    ux_=px4[0]; FDOT4(fw0,0, ux_) ux_=px4[1]; FDOT4(fw0,4, ux_) \
    ux_=px4[2]; FDOT4(fw0,8, ux_) ux_=px4[3]; FDOT4(fw0,12,ux_) \
    ux_=px4[4]; FDOT4(fw1,0, ux_) ux_=px4[5]; FDOT4(fw1,4, ux_) \
    ux_=px4[6]; FDOT4(fw1,8, ux_) ux_=px4[7]; FDOT4(fw1,12,ux_) }

__global__ __launch_bounds__(NT, 3) void rac_kernel(
    const float* __restrict__ x,    const float* __restrict__ hx,
    const int*   __restrict__ done, const float* __restrict__ Wf,
    const float* __restrict__ bfe,  const float* __restrict__ gf,
    const float* __restrict__ btf,  const float* __restrict__ Wih,
    const float* __restrict__ Whh,  const float* __restrict__ bih,
    const float* __restrict__ bhh,  const float* __restrict__ gr,
    const float* __restrict__ btr,  const float* __restrict__ Wp,
    const float* __restrict__ bp,   const float* __restrict__ Wv,
    const float* __restrict__ bv,   float* __restrict__ out)
{
    const int tid = threadIdx.x;
    const int b0  = blockIdx.x * 2;

    __shared__ __align__(16) _Float16 zh[2][HH];
    __shared__ __align__(16) _Float16 hsh[2][HH];
    __shared__ __align__(16) _Float16 xh[2][SS];
    __shared__ __align__(16) float gxl[2][3*HH];
    __shared__ __align__(16) float ghl[2][3*HH];
    __shared__ __align__(16) float yl[2][HH];
    __shared__ __align__(16) float fraw[2][HH];
    __shared__ float fred[4][2];
    __shared__ float hred[4][2];
    __shared__ int   dsh[2][TT];          // done staged once

    const bool isGate = tid < 256;
    const bool isProd = tid < 384;
    const bool isFeat = tid >= 512;
    const bool isXld  = (tid >= 512) && (tid < 640);
    const bool isHead = tid >= 512;

    // ---- main matvec row: 4 f16v = 64 VGPR, pure SSA ----
    f16v w0, w1, w2, w3;
    {
        const float* wsrc = isProd ? (Wih + tid * HH) : (Whh + (tid - 384) * HH);
        const float2* p2 = (const float2*)wsrc;
        LDW16(w0, p2, 0) LDW16(w1, p2, 16) LDW16(w2, p2, 32) LDW16(w3, p2, 48)
    }
    const float bias_mv = isProd ? bih[tid] : bhh[tid - 384];

    // ---- feature row (threads 512-767): 2 f16v = 32 VGPR ----
    f16v fw0 = 0.f, fw1 = 0.f;
    float bfr = 0.f;
    int fc = 0, fj = 0;
    if (isFeat) {
        fc = (tid - 512) >> 7; fj = (tid - 512) & 127;
        const float2* p2 = (const float2*)(Wf + fj * SS);
        LDW16(fw0, p2, 0) LDW16(fw1, p2, 16)
        bfr = bfe[fj];
    }

    // ---- gate regs ----
    int gc = 0, gj = 0;
    float gfr = 0.f, btfr = 0.f, grr = 0.f, btrr = 0.f, hprev = 0.f;
    if (isGate) {
        gc = tid >> 7; gj = tid & 127;
        gfr = gf[gj]; btfr = btf[gj]; grr = gr[gj]; btrr = btr[gj];
        hprev = hx[(b0 + gc) * HH + gj];
        hsh[gc][gj] = (_Float16)hprev;
    }

    // ---- head regs (threads 512-767, 16 groups of 16; groups 0,1 double) ----
    f8v hw0 = 0.f, hw1 = 0.f;
    float bp0 = 0.f, bp1 = 0.f;
    int hi16 = 0, tk0 = 0, tk1 = -1;
    if (isHead) {
        int hid = tid - 512; int hg = hid >> 4; hi16 = hid & 15;
        tk0 = hg; tk1 = (hg < 2) ? (16 + hg) : -1;
        {
            int k = tk0 % 9;
            const float* wr = (k < 8) ? (Wp + k * HH) : Wv;
            hw0[0]=wr[hi16*8+0]; hw0[1]=wr[hi16*8+1]; hw0[2]=wr[hi16*8+2]; hw0[3]=wr[hi16*8+3];
            hw0[4]=wr[hi16*8+4]; hw0[5]=wr[hi16*8+5]; hw0[6]=wr[hi16*8+6]; hw0[7]=wr[hi16*8+7];
            bp0 = (k < 8) ? bp[k] : bv[0];
        }
        if (tk1 >= 0) {
            int k = tk1 % 9;
            const float* wr = (k < 8) ? (Wp + k * HH) : Wv;
            hw1[0]=wr[hi16*8+0]; hw1[1]=wr[hi16*8+1]; hw1[2]=wr[hi16*8+2]; hw1[3]=wr[hi16*8+3];
            hw1[4]=wr[hi16*8+4]; hw1[5]=wr[hi16*8+5]; hw1[6]=wr[hi16*8+6]; hw1[7]=wr[hi16*8+7];
            bp1 = (k < 8) ? bp[k] : bv[0];
        }
    }

    // ---- done staging ----
    for (int idx = tid; idx < 2 * TT; idx += NT)
        dsh[idx >> 9][idx & 511] = done[(b0 + (idx >> 9)) * TT + (idx & 511)];

    // ---- x prefetch regs (threads 512-639) ----
    int xc = 0, xe = 0;
    const float* xbase = nullptr;
    float xr0 = 0.f, xr1 = 0.f;
    if (isXld) {
        int xi = tid - 512; xc = xi >> 6; xe = xi & 63;
        xbase = x + (size_t)(b0 + xc) * TT * SS + xe;
        float xa = xbase[0];
        xr1 = xbase[SS];
        xr0 = xbase[2 * SS];
        xh[xc][xe] = (_Float16)xa;
    }
    __syncthreads();   // P0

    // ---- prologue: z_0 raw ----
    if (isFeat) {
        float f0 = bfr, f1 = 0.f;
        const float4* px4 = (const float4*)xh[fc];
        FEATMV
        float fv = f0 + f1;
        fraw[fc][fj] = fv;
        float s = fv, q = fv * fv;
        #pragma unroll
        for (int m = 1; m < 64; m <<= 1) { s += __shfl_xor(s, m); q += __shfl_xor(q, m); }
        if ((tid & 63) == 0) { int w = (tid >> 6) - 8; fred[w][0] = s; fred[w][1] = q; }
    }
    __syncthreads();   // P1
    if (isGate) {
        float s = fred[2 * gc][0] + fred[2 * gc + 1][0];
        float q = fred[2 * gc][1] + fred[2 * gc + 1][1];
        float mu = s * (1.f / 128.f);
        float rstd = rsqrtf(q * (1.f / 128.f) - mu * mu + 1e-5f);
        float z = (fraw[gc][gj] - mu) * rstd * gfr + btfr;
        zh[gc][gj] = (_Float16)fmaxf(z, 0.f);
    }
    if (isXld) xh[xc][xe] = (_Float16)xr1;   // stage x(1)
    __syncthreads();   // P2

    float hnew_keep = 0.f;
    const int VALO = BB * TT * AA;
    const int HFIN = VALO + BB * TT;

    for (int i = 0; i <= TT; ++i) {
        const bool live = i < TT;
        // ================= Seg A =================
        if (isXld && i < TT - 3) {
            float v = xbase[(size_t)(i + 3) * SS];
            if (((i + 3) & 1) == 0) xr0 = v; else xr1 = v;
        }
        if (isGate && i >= 1) {   // finalize y_{i-1}
            float s = hred[2 * gc][0] + hred[2 * gc + 1][0];
            float q = hred[2 * gc][1] + hred[2 * gc + 1][1];
            float mu = s * (1.f / 128.f);
            float rstd = rsqrtf(q * (1.f / 128.f) - mu * mu + 1e-5f);
            yl[gc][gj] = (hnew_keep - mu) * rstd * grr + btrr;
        }
        if (live) {   // main matvecs, both chains (ILP 2)
            const float4* pa4; const float4* pb4; int r;
            if (isProd) { pa4 = (const float4*)zh[0];  pb4 = (const float4*)zh[1];  r = tid; }
            else        { pa4 = (const float4*)hsh[0]; pb4 = (const float4*)hsh[1]; r = tid - 384; }
            float a0 = bias_mv, a1 = bias_mv;
            MVC(w0, 0) MVC(w1, 4) MVC(w2, 8) MVC(w3, 12)
            if (isProd) { gxl[0][r] = a0; gxl[1][r] = a1; }
            else        { ghl[0][r] = a0; ghl[1][r] = a1; }
        }
        if (isFeat && i < TT - 1) {   // feature dots for z_{i+1}
            float f0 = bfr, f1 = 0.f;
            const float4* px4 = (const float4*)xh[fc];
            FEATMV
            float fv = f0 + f1;
            fraw[fc][fj] = fv;
            float s = fv, q = fv * fv;
            #pragma unroll
            for (int m = 1; m < 64; m <<= 1) { s += __shfl_xor(s, m); q += __shfl_xor(q, m); }
            if ((tid & 63) == 0) { int w = (tid >> 6) - 8; fred[w][0] = s; fred[w][1] = q; }
        }
        __syncthreads();
        // ================= Seg B =================
        if (isGate) {
            if (i < TT - 1) {   // LN+relu -> z_{i+1}
                float s = fred[2 * gc][0] + fred[2 * gc + 1][0];
                float q = fred[2 * gc][1] + fred[2 * gc + 1][1];
                float mu = s * (1.f / 128.f);
                float rstd = rsqrtf(q * (1.f / 128.f) - mu * mu + 1e-5f);
                float z = (fraw[gc][gj] - mu) * rstd * gfr + btfr;
                zh[gc][gj] = (_Float16)fmaxf(z, 0.f);
            }
            if (live) {         // GRU gates for step i
                float xr_ = gxl[gc][gj],          hr_ = ghl[gc][gj];
                float xz_ = gxl[gc][HH + gj],     hz_ = ghl[gc][HH + gj];
                float xn_ = gxl[gc][2 * HH + gj], hn_ = ghl[gc][2 * HH + gj];
                float r_ = 1.f / (1.f + __expf(-(xr_ + hr_)));
                float u_ = 1.f / (1.f + __expf(-(xz_ + hz_)));
                float a_ = xn_ + r_ * hn_;
                a_ = fminf(fmaxf(a_, -20.f), 20.f);
                float e2 = __expf(2.f * a_);
                float n_ = (e2 - 1.f) / (e2 + 1.f);
                float hn2 = (1.f - u_) * n_ + u_ * hprev;
                hnew_keep = hn2;
                float s = hn2, q = hn2 * hn2;
                #pragma unroll
                for (int m = 1; m < 64; m <<= 1) { s += __shfl_xor(s, m); q += __shfl_xor(q, m); }
                if ((tid & 63) == 0) { int w = tid >> 6; hred[w][0] = s; hred[w][1] = q; }
                float hm = hn2 * (dsh[gc][i] ? 0.f : 1.f);
                hprev = hm;
                hsh[gc][gj] = (_Float16)hm;
                if (i == TT - 1) out[HFIN + (b0 + gc) * HH + gj] = hm;
            }
        }
        if (isHead && i >= 1) {   // heads for t = i-1
            int t = i - 1;
            {
                int c = tk0 / 9, k = tk0 % 9;
                const float4* py = (const float4*)yl[c];
                float4 y0 = py[hi16 * 2], y1 = py[hi16 * 2 + 1];
                float p = y0.x*hw0[0] + y0.y*hw0[1] + y0.z*hw0[2] + y0.w*hw0[3]
                        + y1.x*hw0[4] + y1.y*hw0[5] + y1.z*hw0[6] + y1.w*hw0[7];
                #pragma unroll
                for (int m = 8; m >= 1; m >>= 1) p += __shfl_xor(p, m);
                if (hi16 == 0) {
                    int bc = b0 + c;
                    if (k < 8) out[((size_t)bc * TT + t) * AA + k] = p + bp0;
                    else       out[VALO + bc * TT + t] = p + bp0;
                }
            }
            if (tk1 >= 0) {
                int c = tk1 / 9, k = tk1 % 9;
                const float4* py = (const float4*)yl[c];
                float4 y0 = py[hi16 * 2], y1 = py[hi16 * 2 + 1];
                float p = y0.x*hw1[0] + y0.y*hw1[1] + y0.z*hw1[2] + y0.w*hw1[3]
                        + y1.x*hw1[4] + y1.y*hw1[5] + y1.z*hw1[6] + y1.w*hw1[7];
                #pragma unroll
                for (int m = 8; m >= 1; m >>= 1) p += __shfl_xor(p, m);
                if (hi16 == 0) {
                    int bc = b0 + c;
                    if (k < 8) out[((size_t)bc * TT + t) * AA + k] = p + bp1;
                    else       out[VALO + bc * TT + t] = p + bp1;
                }
            }
        }
        if (isXld && i < TT - 2) {   // stage x(i+2)
            float v = (((i + 2) & 1) == 0) ? xr0 : xr1;
            xh[xc][xe] = (_Float16)v;
        }
        __syncthreads();
    }
}

extern "C" void kernel_launch(void* const* d_in, const int* in_sizes, int n_in,
                              void* d_out, int out_size, void* d_ws, size_t ws_size,
                              hipStream_t stream) {
    const float* x   = (const float*)d_in[0];
    const float* hx  = (const float*)d_in[1];
    const int*   dn  = (const int*)d_in[2];
    const float* Wf  = (const float*)d_in[3];
    const float* bfe = (const float*)d_in[4];
    const float* gf  = (const float*)d_in[5];
    const float* btf = (const float*)d_in[6];
    const float* Wih = (const float*)d_in[7];
    const float* Whh = (const float*)d_in[8];
    const float* bih = (const float*)d_in[9];
    const float* bhh = (const float*)d_in[10];
    const float* gr  = (const float*)d_in[11];
    const float* btr = (const float*)d_in[12];
    const float* Wp  = (const float*)d_in[13];
    const float* bp  = (const float*)d_in[14];
    const float* Wv  = (const float*)d_in[15];
    const float* bv  = (const float*)d_in[16];
    float* out = (float*)d_out;

    hipLaunchKernelGGL(rac_kernel, dim3(BB / 2), dim3(NT), 0, stream,
                       x, hx, dn, Wf, bfe, gf, btf, Wih, Whh, bih, bhh,
                       gr, btr, Wp, bp, Wv, bv, out);
}

// Round 6
// 1686.150 us; speedup vs baseline: 1.4784x; 1.1484x over previous
//
#include <hip/hip_runtime.h>

// RecurrentActorCritic B=512,T=512,S=64,H=128,A=8 (fp32 I/O).
// Grid 256 x 768 threads, one block/CU, two batch chains per block.
// R2-R5 post-mortem: VGPR_Count pinned at 84 (= 512/6, a 2-blocks/CU
// occupancy target) across four different weight encodings -> the compiler's
// register BUDGET, not SROA, forced ~115 GB/dispatch of spill traffic.
// R6: pin budget via amdgpu_waves_per_eu(3,3) + flat_work_group_size(768,768)
// (no __launch_bounds__) -> 170 VGPRs, union-of-roles ~137 regs fits.
// Weights stay ext_vector SSA (f16v = 16 floats, each = packed fp16 pair),
// literal-constant lane access only; LDS operands read as float4 broadcasts.
// Roles: tid 0-255 gate/LN + W_ih rows 0-255; 256-383 W_ih rows + feature;
// 384-511 W_hh rows + feature; 512-767 W_hh rows + heads; 512-639 x prefetch.

typedef _Float16 h2t __attribute__((ext_vector_type(2)));
typedef float f16v __attribute__((ext_vector_type(16)));
typedef float f8v  __attribute__((ext_vector_type(8)));

__device__ __forceinline__ float dot2a(h2t a, h2t b, float c) {
    return __builtin_amdgcn_fdot2(a, b, c, false);
}
__device__ __forceinline__ h2t f2h(float f) { return __builtin_bit_cast(h2t, f); }
__device__ __forceinline__ float pk2(float lo, float hi) {
    h2t a; a.x = (_Float16)lo; a.y = (_Float16)hi;
    return __builtin_bit_cast(float, a);
}

#define BB 512
#define TT 512
#define SS 64
#define HH 128
#define AA 8
#define NT 768

#define LDW16(WV, P2, OFS) { float2 v_; \
    v_=(P2)[(OFS)+0];  WV[0] =pk2(v_.x,v_.y); v_=(P2)[(OFS)+1];  WV[1] =pk2(v_.x,v_.y); \
    v_=(P2)[(OFS)+2];  WV[2] =pk2(v_.x,v_.y); v_=(P2)[(OFS)+3];  WV[3] =pk2(v_.x,v_.y); \
    v_=(P2)[(OFS)+4];  WV[4] =pk2(v_.x,v_.y); v_=(P2)[(OFS)+5];  WV[5] =pk2(v_.x,v_.y); \
    v_=(P2)[(OFS)+6];  WV[6] =pk2(v_.x,v_.y); v_=(P2)[(OFS)+7];  WV[7] =pk2(v_.x,v_.y); \
    v_=(P2)[(OFS)+8];  WV[8] =pk2(v_.x,v_.y); v_=(P2)[(OFS)+9];  WV[9] =pk2(v_.x,v_.y); \
    v_=(P2)[(OFS)+10]; WV[10]=pk2(v_.x,v_.y); v_=(P2)[(OFS)+11]; WV[11]=pk2(v_.x,v_.y); \
    v_=(P2)[(OFS)+12]; WV[12]=pk2(v_.x,v_.y); v_=(P2)[(OFS)+13]; WV[13]=pk2(v_.x,v_.y); \
    v_=(P2)[(OFS)+14]; WV[14]=pk2(v_.x,v_.y); v_=(P2)[(OFS)+15]; WV[15]=pk2(v_.x,v_.y); }

#define DOT4(WV, J, UA, UB) \
    a0=dot2a(f2h(WV[(J)+0]),f2h(UA.x),a0); a1=dot2a(f2h(WV[(J)+0]),f2h(UB.x),a1); \
    a0=dot2a(f2h(WV[(J)+1]),f2h(UA.y),a0); a1=dot2a(f2h(WV[(J)+1]),f2h(UB.y),a1); \
    a0=dot2a(f2h(WV[(J)+2]),f2h(UA.z),a0); a1=dot2a(f2h(WV[(J)+2]),f2h(UB.z),a1); \
    a0=dot2a(f2h(WV[(J)+3]),f2h(UA.w),a0); a1=dot2a(f2h(WV[(J)+3]),f2h(UB.w),a1);

#define MVC(WV, OFS) { float4 ua_, ub_; \
    ua_=pa4[(OFS)+0]; ub_=pb4[(OFS)+0]; DOT4(WV,0, ua_,ub_) \
    ua_=pa4[(OFS)+1]; ub_=pb4[(OFS)+1]; DOT4(WV,4, ua_,ub_) \
    ua_=pa4[(OFS)+2]; ub_=pb4[(OFS)+2]; DOT4(WV,8, ua_,ub_) \
    ua_=pa4[(OFS)+3]; ub_=pb4[(OFS)+3]; DOT4(WV,12,ua_,ub_) }

#define FDOT4(WV, J, UX) \
    f0=dot2a(f2h(WV[(J)+0]),f2h(UX.x),f0); f1=dot2a(f2h(WV[(J)+1]),f2h(UX.y),f1); \
    f0=dot2a(f2h(WV[(J)+2]),f2h(UX.z),f0); f1=dot2a(f2h(WV[(J)+3]),f2h(UX.w),f1);

#define FEATMV { float4 ux_; \
    ux_=px4[0]; FDOT4(fw0,0, ux_) ux_=px4[1]; FDOT4(fw0,4, ux_) \
    ux_=px4[2]; FDOT4(fw0,8, ux_) ux_=px4[3]; FDOT4(fw0,12,ux_) \
    ux_=px4[4]; FDOT4(fw1,0, ux_) ux_=px4[5]; FDOT4(fw1,4, ux_) \
    ux_=px4[6]; FDOT4(fw1,8, ux_) ux_=px4[7]; FDOT4(fw1,12,ux_) }

__global__ void
__attribute__((amdgpu_flat_work_group_size(NT, NT), amdgpu_waves_per_eu(3, 3)))
rac_kernel(
    const float* __restrict__ x,    const float* __restrict__ hx,
    const int*   __restrict__ done, const float* __restrict__ Wf,
    const float* __restrict__ bfe,  const float* __restrict__ gf,
    const float* __restrict__ btf,  const float* __restrict__ Wih,
    const float* __restrict__ Whh,  const float* __restrict__ bih,
    const float* __restrict__ bhh,  const float* __restrict__ gr,
    const float* __restrict__ btr,  const float* __restrict__ Wp,
    const float* __restrict__ bp,   const float* __restrict__ Wv,
    const float* __restrict__ bv,   float* __restrict__ out)
{
    const int tid = threadIdx.x;
    const int b0  = blockIdx.x * 2;

    __shared__ __align__(16) _Float16 zh[2][HH];
    __shared__ __align__(16) _Float16 hsh[2][HH];
    __shared__ __align__(16) _Float16 xh[2][SS];
    __shared__ __align__(16) float gxl[2][3*HH];
    __shared__ __align__(16) float ghl[2][3*HH];
    __shared__ __align__(16) float yl[2][HH];
    __shared__ __align__(16) float fraw[2][HH];
    __shared__ float fred[4][2];
    __shared__ float hred[4][2];
    __shared__ int   dsh[2][TT];

    const bool isGate = tid < 256;
    const bool isProd = tid < 384;
    const bool isFeat = (tid >= 256) && (tid < 512);
    const bool isXld  = (tid >= 512) && (tid < 640);
    const bool isHead = tid >= 512;

    // ---- main matvec row: 4 f16v = 64 VGPR, pure SSA ----
    f16v w0, w1, w2, w3;
    {
        const float* wsrc = isProd ? (Wih + tid * HH) : (Whh + (tid - 384) * HH);
        const float2* p2 = (const float2*)wsrc;
        LDW16(w0, p2, 0) LDW16(w1, p2, 16) LDW16(w2, p2, 32) LDW16(w3, p2, 48)
    }
    const float bias_mv = isProd ? bih[tid] : bhh[tid - 384];

    // ---- feature row (threads 256-511): 2 f16v = 32 VGPR ----
    f16v fw0 = 0.f, fw1 = 0.f;
    float bfr = 0.f;
    int fc = 0, fj = 0;
    if (isFeat) {
        fc = (tid - 256) >> 7; fj = (tid - 256) & 127;
        const float2* p2 = (const float2*)(Wf + fj * SS);
        LDW16(fw0, p2, 0) LDW16(fw1, p2, 16)
        bfr = bfe[fj];
    }

    // ---- gate regs ----
    int gc = 0, gj = 0;
    float gfr = 0.f, btfr = 0.f, grr = 0.f, btrr = 0.f, hprev = 0.f;
    if (isGate) {
        gc = tid >> 7; gj = tid & 127;
        gfr = gf[gj]; btfr = btf[gj]; grr = gr[gj]; btrr = btr[gj];
        hprev = hx[(b0 + gc) * HH + gj];
        hsh[gc][gj] = (_Float16)hprev;
    }

    // ---- head regs (threads 512-767, 16 groups of 16; groups 0,1 double) ----
    f8v hw0 = 0.f, hw1 = 0.f;
    float bp0 = 0.f, bp1 = 0.f;
    int hi16 = 0, tk0 = 0, tk1 = -1;
    if (isHead) {
        int hid = tid - 512; int hg = hid >> 4; hi16 = hid & 15;
        tk0 = hg; tk1 = (hg < 2) ? (16 + hg) : -1;
        {
            int k = tk0 % 9;
            const float* wr = (k < 8) ? (Wp + k * HH) : Wv;
            hw0[0]=wr[hi16*8+0]; hw0[1]=wr[hi16*8+1]; hw0[2]=wr[hi16*8+2]; hw0[3]=wr[hi16*8+3];
            hw0[4]=wr[hi16*8+4]; hw0[5]=wr[hi16*8+5]; hw0[6]=wr[hi16*8+6]; hw0[7]=wr[hi16*8+7];
            bp0 = (k < 8) ? bp[k] : bv[0];
        }
        if (tk1 >= 0) {
            int k = tk1 % 9;
            const float* wr = (k < 8) ? (Wp + k * HH) : Wv;
            hw1[0]=wr[hi16*8+0]; hw1[1]=wr[hi16*8+1]; hw1[2]=wr[hi16*8+2]; hw1[3]=wr[hi16*8+3];
            hw1[4]=wr[hi16*8+4]; hw1[5]=wr[hi16*8+5]; hw1[6]=wr[hi16*8+6]; hw1[7]=wr[hi16*8+7];
            bp1 = (k < 8) ? bp[k] : bv[0];
        }
    }

    // ---- done staging ----
    for (int idx = tid; idx < 2 * TT; idx += NT)
        dsh[idx >> 9][idx & 511] = done[(b0 + (idx >> 9)) * TT + (idx & 511)];

    // ---- x prefetch regs (threads 512-639) ----
    int xc = 0, xe = 0;
    const float* xbase = nullptr;
    float xr0 = 0.f, xr1 = 0.f;
    if (isXld) {
        int xi = tid - 512; xc = xi >> 6; xe = xi & 63;
        xbase = x + (size_t)(b0 + xc) * TT * SS + xe;
        float xa = xbase[0];
        xr1 = xbase[SS];
        xr0 = xbase[2 * SS];
        xh[xc][xe] = (_Float16)xa;
    }
    __syncthreads();   // P0

    // ---- prologue: z_0 raw ----
    if (isFeat) {
        float f0 = bfr, f1 = 0.f;
        const float4* px4 = (const float4*)xh[fc];
        FEATMV
        float fv = f0 + f1;
        fraw[fc][fj] = fv;
        float s = fv, q = fv * fv;
        #pragma unroll
        for (int m = 1; m < 64; m <<= 1) { s += __shfl_xor(s, m); q += __shfl_xor(q, m); }
        if ((tid & 63) == 0) { int w = (tid >> 6) - 4; fred[w][0] = s; fred[w][1] = q; }
    }
    __syncthreads();   // P1
    if (isGate) {
        float s = fred[2 * gc][0] + fred[2 * gc + 1][0];
        float q = fred[2 * gc][1] + fred[2 * gc + 1][1];
        float mu = s * (1.f / 128.f);
        float rstd = rsqrtf(q * (1.f / 128.f) - mu * mu + 1e-5f);
        float z = (fraw[gc][gj] - mu) * rstd * gfr + btfr;
        zh[gc][gj] = (_Float16)fmaxf(z, 0.f);
    }
    if (isXld) xh[xc][xe] = (_Float16)xr1;   // stage x(1)
    __syncthreads();   // P2

    float hnew_keep = 0.f;
    const int VALO = BB * TT * AA;
    const int HFIN = VALO + BB * TT;

    for (int i = 0; i <= TT; ++i) {
        const bool live = i < TT;
        // ================= Seg A =================
        if (isXld && i < TT - 3) {
            float v = xbase[(size_t)(i + 3) * SS];
            if (((i + 3) & 1) == 0) xr0 = v; else xr1 = v;
        }
        if (isGate && i >= 1) {   // finalize y_{i-1}
            float s = hred[2 * gc][0] + hred[2 * gc + 1][0];
            float q = hred[2 * gc][1] + hred[2 * gc + 1][1];
            float mu = s * (1.f / 128.f);
            float rstd = rsqrtf(q * (1.f / 128.f) - mu * mu + 1e-5f);
            yl[gc][gj] = (hnew_keep - mu) * rstd * grr + btrr;
        }
        if (live) {   // main matvecs, both chains (ILP 2)
            const float4* pa4; const float4* pb4; int r;
            if (isProd) { pa4 = (const float4*)zh[0];  pb4 = (const float4*)zh[1];  r = tid; }
            else        { pa4 = (const float4*)hsh[0]; pb4 = (const float4*)hsh[1]; r = tid - 384; }
            float a0 = bias_mv, a1 = bias_mv;
            MVC(w0, 0) MVC(w1, 4) MVC(w2, 8) MVC(w3, 12)
            if (isProd) { gxl[0][r] = a0; gxl[1][r] = a1; }
            else        { ghl[0][r] = a0; ghl[1][r] = a1; }
        }
        if (isFeat && i < TT - 1) {   // feature dots for z_{i+1}
            float f0 = bfr, f1 = 0.f;
            const float4* px4 = (const float4*)xh[fc];
            FEATMV
            float fv = f0 + f1;
            fraw[fc][fj] = fv;
            float s = fv, q = fv * fv;
            #pragma unroll
            for (int m = 1; m < 64; m <<= 1) { s += __shfl_xor(s, m); q += __shfl_xor(q, m); }
            if ((tid & 63) == 0) { int w = (tid >> 6) - 4; fred[w][0] = s; fred[w][1] = q; }
        }
        __syncthreads();
        // ================= Seg B =================
        if (isGate) {
            if (i < TT - 1) {   // LN+relu -> z_{i+1}
                float s = fred[2 * gc][0] + fred[2 * gc + 1][0];
                float q = fred[2 * gc][1] + fred[2 * gc + 1][1];
                float mu = s * (1.f / 128.f);
                float rstd = rsqrtf(q * (1.f / 128.f) - mu * mu + 1e-5f);
                float z = (fraw[gc][gj] - mu) * rstd * gfr + btfr;
                zh[gc][gj] = (_Float16)fmaxf(z, 0.f);
            }
            if (live) {         // GRU gates for step i
                float xr_ = gxl[gc][gj],          hr_ = ghl[gc][gj];
                float xz_ = gxl[gc][HH + gj],     hz_ = ghl[gc][HH + gj];
                float xn_ = gxl[gc][2 * HH + gj], hn_ = ghl[gc][2 * HH + gj];
                float r_ = 1.f / (1.f + __expf(-(xr_ + hr_)));
                float u_ = 1.f / (1.f + __expf(-(xz_ + hz_)));
                float a_ = xn_ + r_ * hn_;
                a_ = fminf(fmaxf(a_, -20.f), 20.f);
                float e2 = __expf(2.f * a_);
                float n_ = (e2 - 1.f) / (e2 + 1.f);
                float hn2 = (1.f - u_) * n_ + u_ * hprev;
                hnew_keep = hn2;
                float s = hn2, q = hn2 * hn2;
                #pragma unroll
                for (int m = 1; m < 64; m <<= 1) { s += __shfl_xor(s, m); q += __shfl_xor(q, m); }
                if ((tid & 63) == 0) { int w = tid >> 6; hred[w][0] = s; hred[w][1] = q; }
                float hm = hn2 * (dsh[gc][i] ? 0.f : 1.f);
                hprev = hm;
                hsh[gc][gj] = (_Float16)hm;
                if (i == TT - 1) out[HFIN + (b0 + gc) * HH + gj] = hm;
            }
        }
        if (isHead && i >= 1) {   // heads for t = i-1
            int t = i - 1;
            {
                int c = tk0 / 9, k = tk0 % 9;
                const float4* py = (const float4*)yl[c];
                float4 y0 = py[hi16 * 2], y1 = py[hi16 * 2 + 1];
                float p = y0.x*hw0[0] + y0.y*hw0[1] + y0.z*hw0[2] + y0.w*hw0[3]
                        + y1.x*hw0[4] + y1.y*hw0[5] + y1.z*hw0[6] + y1.w*hw0[7];
                #pragma unroll
                for (int m = 8; m >= 1; m >>= 1) p += __shfl_xor(p, m);
                if (hi16 == 0) {
                    int bc = b0 + c;
                    if (k < 8) out[((size_t)bc * TT + t) * AA + k] = p + bp0;
                    else       out[VALO + bc * TT + t] = p + bp0;
                }
            }
            if (tk1 >= 0) {
                int c = tk1 / 9, k = tk1 % 9;
                const float4* py = (const float4*)yl[c];
                float4 y0 = py[hi16 * 2], y1 = py[hi16 * 2 + 1];
                float p = y0.x*hw1[0] + y0.y*hw1[1] + y0.z*hw1[2] + y0.w*hw1[3]
                        + y1.x*hw1[4] + y1.y*hw1[5] + y1.z*hw1[6] + y1.w*hw1[7];
                #pragma unroll
                for (int m = 8; m >= 1; m >>= 1) p += __shfl_xor(p, m);
                if (hi16 == 0) {
                    int bc = b0 + c;
                    if (k < 8) out[((size_t)bc * TT + t) * AA + k] = p + bp1;
                    else       out[VALO + bc * TT + t] = p + bp1;
                }
            }
        }
        if (isXld && i < TT - 2) {   // stage x(i+2)
            float v = (((i + 2) & 1) == 0) ? xr0 : xr1;
            xh[xc][xe] = (_Float16)v;
        }
        __syncthreads();
    }
}

extern "C" void kernel_launch(void* const* d_in, const int* in_sizes, int n_in,
                              void* d_out, int out_size, void* d_ws, size_t ws_size,
                              hipStream_t stream) {
    const float* x   = (const float*)d_in[0];
    const float* hx  = (const float*)d_in[1];
    const int*   dn  = (const int*)d_in[2];
    const float* Wf  = (const float*)d_in[3];
    const float* bfe = (const float*)d_in[4];
    const float* gf  = (const float*)d_in[5];
    const float* btf = (const float*)d_in[6];
    const float* Wih = (const float*)d_in[7];
    const float* Whh = (const float*)d_in[8];
    const float* bih = (const float*)d_in[9];
    const float* bhh = (const float*)d_in[10];
    const float* gr  = (const float*)d_in[11];
    const float* btr = (const float*)d_in[12];
    const float* Wp  = (const float*)d_in[13];
    const float* bp  = (const float*)d_in[14];
    const float* Wv  = (const float*)d_in[15];
    const float* bv  = (const float*)d_in[16];
    float* out = (float*)d_out;

    hipLaunchKernelGGL(rac_kernel, dim3(BB / 2), dim3(NT), 0, stream,
                       x, hx, dn, Wf, bfe, gf, btf, Wih, Whh, bih, bhh,
                       gr, btr, Wp, bp, Wv, bv, out);
}